// Round 8
// baseline (338.723 us; speedup 1.0000x reference)
//
#include <hip/hip_runtime.h>

typedef __attribute__((ext_vector_type(8))) _Float16 f16x8;
typedef __attribute__((ext_vector_type(16))) float   f32x16;
typedef unsigned int u32;

#define NPTS 65536
#define ROWS   256      // query rows per block
#define CH     1024     // target cols staged in LDS per chunk
#define JSLICE 8192     // target cols scanned per block

__device__ __forceinline__ u32 umin2(u32 a, u32 b) { return a < b ? a : b; }

// ---------------------------------------------------------------------------
// Packing math (round-3-verified on hardware, absmax 0.0):
//  d(a,b) = |a|^2 + |b|^2 - 2 a.b via ONE K=16 f16 MFMA; |a|^2 now enters
//  through the MFMA C-operand (C/D are separate register fields, no copies).
//  Q frag: h0:[xh,yh,zh, xl,yl,zl, xh,yh]  h1:[zh, xl,yl,zl, 1,1,1, 0]
//  T frag: h0:[cx,cy,cz, cx,cy,cz, dx,dy]  h1:[dz, dx,dy,dz, q0,q1,q2, 0]
//  c* = -2*high(b), d* = -2*low(b), q0+q1+q2 = |b|^2 (3-term f16 split).
// ---------------------------------------------------------------------------
__device__ __forceinline__ void pack_target_frags(float x, float y, float z,
                                                  f16x8& t0, f16x8& t1)
{
    const _Float16 xh = (_Float16)x, yh = (_Float16)y, zh = (_Float16)z;
    const _Float16 xl = (_Float16)(x - (float)xh);
    const _Float16 yl = (_Float16)(y - (float)yh);
    const _Float16 zl = (_Float16)(z - (float)zh);
    const _Float16 cx = (_Float16)(-2.0f * (float)xh);
    const _Float16 cy = (_Float16)(-2.0f * (float)yh);
    const _Float16 cz = (_Float16)(-2.0f * (float)zh);
    const _Float16 dx = (_Float16)(-2.0f * (float)xl);
    const _Float16 dy = (_Float16)(-2.0f * (float)yl);
    const _Float16 dz = (_Float16)(-2.0f * (float)zl);
    const float sq = fmaf(z, z, fmaf(y, y, x * x));
    const _Float16 q0 = (_Float16)sq;
    const float    r1 = sq - (float)q0;
    const _Float16 q1 = (_Float16)r1;
    const _Float16 q2 = (_Float16)(r1 - (float)q1);
    const f16x8 a = {cx, cy, cz, cx, cy, cz, dx, dy};
    const f16x8 b = {dz, dx, dy, dz, q0, q1, q2, (_Float16)0.0f};
    t0 = a; t1 = b;
}

__device__ __forceinline__ f16x8 pack_query_frag(float x, float y, float z, int half)
{
    const _Float16 xh = (_Float16)x, yh = (_Float16)y, zh = (_Float16)z;
    const _Float16 xl = (_Float16)(x - (float)xh);
    const _Float16 yl = (_Float16)(y - (float)yh);
    const _Float16 zl = (_Float16)(z - (float)zh);
    const _Float16 one = (_Float16)1.0f, zero = (_Float16)0.0f;
    if (half == 0) { const f16x8 v = {xh, yh, zh, xl, yl, zl, xh, yh}; return v; }
    const f16x8 v = {zh, xl, yl, zl, one, one, one, zero}; return v;
}

// Round-3 structure (proven). NO inline asm anywhere: rounds 4-7 showed that
// inline-asm readers of MFMA-written VGPRs escape the compiler's MFMA hazard
// wait-state insertion -> silent corruption. VALU reduction instead comes
// from (a) |a|^2 in the MFMA C-operand -> outputs are true squared distances,
// (b) min-merge in the unsigned-int domain (free bitcast, no NaN
// canonicalization, umin chains pattern-match to v_min3_u32).
__global__ __launch_bounds__(512) void chamfer_mfma_kernel(
    const float* __restrict__ A, const float* __restrict__ B,
    unsigned int* __restrict__ dmin)
{
    __shared__ _Float16 Al[2 * ROWS * 8];   // 8 KB
    __shared__ float    Aq[ROWS];           // 1 KB
    __shared__ _Float16 Bl[2 * CH * 8];     // 32 KB

    const int bid  = blockIdx.x;            // 0..4095
    const int dir  = bid >> 11;             // 0: A->B, 1: B->A
    const int r2   = bid & 2047;
    const int iblk = r2 >> 3;               // 0..255
    const int jsp  = r2 & 7;                // 0..7

    const float* __restrict__ Q = dir ? B : A;
    const float* __restrict__ T = dir ? A : B;
    unsigned int* __restrict__ dm = dmin + dir * NPTS;

    const int t     = threadIdx.x;
    const int lane  = t & 63;
    const int wid   = t >> 6;               // wave owns rows [wid*32, +32)
    const int half  = lane >> 5;
    const int ibase = iblk * ROWS;
    const int jbase = jsp * JSLICE;

    if (t < ROWS) {
        const float x = Q[(ibase + t) * 3 + 0];
        const float y = Q[(ibase + t) * 3 + 1];
        const float z = Q[(ibase + t) * 3 + 2];
        const f16x8 q0 = pack_query_frag(x, y, z, 0);
        const f16x8 q1 = pack_query_frag(x, y, z, 1);
        *(f16x8*)&Al[t * 8] = q0;
        *(f16x8*)&Al[ROWS * 8 + t * 8] = q1;
        Aq[t] = fmaf(z, z, fmaf(y, y, x * x));
    }
    __syncthreads();

    // A fragment: row = wid*32 + (lane&31), k-half = lane>>5
    const f16x8 af = *(const f16x8*)&Al[half * (ROWS * 8) + (wid * 32 + (lane & 31)) * 8];

    // C-operand: |a|^2 broadcast along cols. C/D layout (round-3-verified):
    // col = lane&31, row = (r&3) + 8*(r>>2) + 4*half.  Broadcast LDS reads.
    f32x16 cq;
#pragma unroll
    for (int r = 0; r < 16; ++r)
        cq[r] = Aq[wid * 32 + (r & 3) + 8 * (r >> 2) + 4 * half];

    u32 rmin[16];
#pragma unroll
    for (int i = 0; i < 16; ++i) rmin[i] = 0x7F7F7F7Fu;   // ~3.39e38 bits

    for (int ch = 0; ch < JSLICE / CH; ++ch) {
        __syncthreads();
#pragma unroll
        for (int pp = 0; pp < 2; ++pp) {
            const int c = t + pp * 512;
            const int g = jbase + ch * CH + c;
            f16x8 t0, t1;
            pack_target_frags(T[g * 3 + 0], T[g * 3 + 1], T[g * 3 + 2], t0, t1);
            *(f16x8*)&Bl[c * 8] = t0;
            *(f16x8*)&Bl[CH * 8 + c * 8] = t1;
        }
        __syncthreads();

#pragma unroll 4
        for (int jt = 0; jt < CH / 32; jt += 2) {
            const f16x8 bf0 = *(const f16x8*)&Bl[half * (CH * 8) + (jt * 32 + (lane & 31)) * 8];
            const f16x8 bf1 = *(const f16x8*)&Bl[half * (CH * 8) + ((jt + 1) * 32 + (lane & 31)) * 8];
            const f32x16 d0 = __builtin_amdgcn_mfma_f32_32x32x16_f16(af, bf0, cq, 0, 0, 0);
            const f32x16 d1 = __builtin_amdgcn_mfma_f32_32x32x16_f16(af, bf1, cq, 0, 0, 0);
#pragma unroll
            for (int r = 0; r < 16; ++r) {
                // true squared distances >= 0 (up to ~1e-5 cancellation, whose
                // negative bit-patterns map to huge uints and are ignored):
                // uint order == float order. umin chain -> v_min3_u32.
                rmin[r] = umin2(rmin[r],
                                umin2(__float_as_uint(d0[r]),
                                      __float_as_uint(d1[r])));
            }
        }
    }

    // min over the 32 col-residues (lane bits 0..4; bit 5 = k-half -> rows)
#pragma unroll
    for (int m = 1; m <= 16; m <<= 1) {
#pragma unroll
        for (int r = 0; r < 16; ++r)
            rmin[r] = umin2(rmin[r], (u32)__shfl_xor((int)rmin[r], m, 64));
    }

    if ((lane & 31) == 0) {
#pragma unroll
        for (int r = 0; r < 16; ++r) {
            const int rl = wid * 32 + (r & 3) + 8 * (r >> 2) + 4 * half;
            atomicMin(&dm[ibase + rl], rmin[r]);
        }
    }
}

// Sum dmin over all 2*65536 queries; out += blockSum / 65536.
__global__ __launch_bounds__(256) void chamfer_reduce_kernel(
    const unsigned int* __restrict__ dmin, float* __restrict__ out)
{
    const int i = blockIdx.x * 256 + threadIdx.x;
    float v = __uint_as_float(dmin[i]);
#pragma unroll
    for (int off = 32; off > 0; off >>= 1)
        v += __shfl_down(v, off, 64);
    __shared__ float ws2[4];
    const int lane = threadIdx.x & 63;
    const int wid  = threadIdx.x >> 6;
    if (lane == 0) ws2[wid] = v;
    __syncthreads();
    if (threadIdx.x == 0)
        atomicAdd(out, (ws2[0] + ws2[1] + ws2[2] + ws2[3]) * (1.0f / (float)NPTS));
}

// ============================================================================
extern "C" void kernel_launch(void* const* d_in, const int* in_sizes, int n_in,
                              void* d_out, int out_size, void* d_ws, size_t ws_size,
                              hipStream_t stream)
{
    const float* A = (const float*)d_in[0];   // pc0 (65536,3) f32
    const float* B = (const float*)d_in[1];   // pc1 (65536,3) f32
    float* out = (float*)d_out;               // scalar f32
    unsigned int* dmin = (unsigned int*)d_ws; // 512 KB, proven sufficient r2/r3

    hipMemsetAsync(dmin, 0x7F, 2 * NPTS * sizeof(unsigned int), stream);
    hipMemsetAsync(out, 0, sizeof(float), stream);

    chamfer_mfma_kernel<<<4096, 512, 0, stream>>>(A, B, dmin);
    chamfer_reduce_kernel<<<(2 * NPTS) / 256, 256, 0, stream>>>(dmin, out);
}

// Round 9
// 270.930 us; speedup vs baseline: 1.2502x; 1.2502x over previous
//
#include <hip/hip_runtime.h>

typedef __attribute__((ext_vector_type(8))) _Float16 f16x8;
typedef __attribute__((ext_vector_type(16))) float   f32x16;
typedef unsigned int u32;

#define NPTS   65536
#define ROWS   512      // query rows per block (8 waves x 64 rows each)
#define CH     1024     // target cols staged in LDS per chunk
#define JSLICE 8192     // target cols scanned per block
#define NIBLK  128      // 65536 / ROWS
#define NJSP   8        // 65536 / JSLICE

// ---------------------------------------------------------------------------
// Packing math (round-3-verified on hardware, absmax 0.0):
//  d(a,b) = |a|^2 + |b|^2 - 2 a.b packed into ONE K=16 f16 MFMA (C=0).
//  Q frag: h0:[xh,yh,zh, xl,yl,zl, xh,yh]  h1:[zh, xl,yl,zl, 1,1,1, 0]
//  T frag: h0:[cx,cy,cz, cx,cy,cz, dx,dy]  h1:[dz, dx,dy,dz, q0,q1,q2, 0]
//  c* = -2*high(b), d* = -2*low(b), q0+q1+q2 = |b|^2 (3-term f16 split).
//  MFMA output = |b|^2 - 2 a.b ; |a|^2 added in f32 epilogue (const per row).
// ---------------------------------------------------------------------------
__device__ __forceinline__ void pack_target_frags(float x, float y, float z,
                                                  f16x8& t0, f16x8& t1)
{
    const _Float16 xh = (_Float16)x, yh = (_Float16)y, zh = (_Float16)z;
    const _Float16 xl = (_Float16)(x - (float)xh);
    const _Float16 yl = (_Float16)(y - (float)yh);
    const _Float16 zl = (_Float16)(z - (float)zh);
    const _Float16 cx = (_Float16)(-2.0f * (float)xh);
    const _Float16 cy = (_Float16)(-2.0f * (float)yh);
    const _Float16 cz = (_Float16)(-2.0f * (float)zh);
    const _Float16 dx = (_Float16)(-2.0f * (float)xl);
    const _Float16 dy = (_Float16)(-2.0f * (float)yl);
    const _Float16 dz = (_Float16)(-2.0f * (float)zl);
    const float sq = fmaf(z, z, fmaf(y, y, x * x));
    const _Float16 q0 = (_Float16)sq;
    const float    r1 = sq - (float)q0;
    const _Float16 q1 = (_Float16)r1;
    const _Float16 q2 = (_Float16)(r1 - (float)q1);
    const f16x8 a = {cx, cy, cz, cx, cy, cz, dx, dy};
    const f16x8 b = {dz, dx, dy, dz, q0, q1, q2, (_Float16)0.0f};
    t0 = a; t1 = b;
}

__device__ __forceinline__ f16x8 pack_query_frag(float x, float y, float z, int half)
{
    const _Float16 xh = (_Float16)x, yh = (_Float16)y, zh = (_Float16)z;
    const _Float16 xl = (_Float16)(x - (float)xh);
    const _Float16 yl = (_Float16)(y - (float)yh);
    const _Float16 zl = (_Float16)(z - (float)zh);
    const _Float16 one = (_Float16)1.0f, zero = (_Float16)0.0f;
    if (half == 0) { const f16x8 v = {xh, yh, zh, xl, yl, zl, xh, yh}; return v; }
    const f16x8 v = {zh, xl, yl, zl, one, one, one, zero}; return v;
}

// Round-3 proven structure + (a) __launch_bounds__(512,2) relaxing the VGPR
// budget to 256 so MFMA dests stay in arch VGPRs (round-8 counters showed
// ~75 VALU instr/iter = AGPR round-trip tax at the default occupancy target),
// (b) 2x row-blocking: each wave owns 64 rows (af0/af1), so each B-fragment
// pair feeds 4 MFMAs -> LDS read traffic per distance halves. NO inline asm
// anywhere (rounds 4-7: asm touching MFMA data corrupts silently).
__global__ __launch_bounds__(512, 2) void chamfer_mfma_kernel(
    const float* __restrict__ A, const float* __restrict__ B,
    unsigned int* __restrict__ dmin)
{
    __shared__ _Float16 Al[2 * ROWS * 8];   // 16 KB
    __shared__ float    Aq[ROWS];           // 2 KB
    __shared__ _Float16 Bl[2 * CH * 8];     // 32 KB  (total 50 KB -> 3 blk/CU)

    const int bid  = blockIdx.x;            // 0..2047
    const int dir  = bid >> 10;             // 0: A->B, 1: B->A
    const int r2   = bid & 1023;
    const int iblk = r2 >> 3;               // 0..127
    const int jsp  = r2 & 7;                // 0..7

    const float* __restrict__ Q = dir ? B : A;
    const float* __restrict__ T = dir ? A : B;
    unsigned int* __restrict__ dm = dmin + dir * NPTS;

    const int t     = threadIdx.x;
    const int lane  = t & 63;
    const int wid   = t >> 6;               // wave owns rows [wid*64, +64)
    const int half  = lane >> 5;
    const int l31   = lane & 31;
    const int ibase = iblk * ROWS;
    const int jbase = jsp * JSLICE;

    // ---- stage A tile: 512 threads -> 512 rows ----
    {
        const float x = Q[(ibase + t) * 3 + 0];
        const float y = Q[(ibase + t) * 3 + 1];
        const float z = Q[(ibase + t) * 3 + 2];
        const f16x8 q0 = pack_query_frag(x, y, z, 0);
        const f16x8 q1 = pack_query_frag(x, y, z, 1);
        *(f16x8*)&Al[t * 8] = q0;
        *(f16x8*)&Al[ROWS * 8 + t * 8] = q1;
        Aq[t] = fmaf(z, z, fmaf(y, y, x * x));
    }
    __syncthreads();

    // A fragments: af0 = rows [wid*64, +32), af1 = rows [wid*64+32, +32)
    const f16x8 af0 = *(const f16x8*)&Al[half * (ROWS * 8) + (wid * 64 + l31) * 8];
    const f16x8 af1 = *(const f16x8*)&Al[half * (ROWS * 8) + (wid * 64 + 32 + l31) * 8];

    f32x16 zc;
#pragma unroll
    for (int i = 0; i < 16; ++i) zc[i] = 0.0f;

    float rminA[16], rminB[16];
#pragma unroll
    for (int i = 0; i < 16; ++i) { rminA[i] = 3.4e38f; rminB[i] = 3.4e38f; }

    for (int ch = 0; ch < JSLICE / CH; ++ch) {
        __syncthreads();
#pragma unroll
        for (int pp = 0; pp < 2; ++pp) {
            const int c = t + pp * 512;
            const int g = jbase + ch * CH + c;
            f16x8 t0, t1;
            pack_target_frags(T[g * 3 + 0], T[g * 3 + 1], T[g * 3 + 2], t0, t1);
            *(f16x8*)&Bl[c * 8] = t0;
            *(f16x8*)&Bl[CH * 8 + c * 8] = t1;
        }
        __syncthreads();

#pragma unroll 2
        for (int jt = 0; jt < CH / 32; jt += 2) {
            const f16x8 bf0 = *(const f16x8*)&Bl[half * (CH * 8) + (jt * 32 + l31) * 8];
            const f16x8 bf1 = *(const f16x8*)&Bl[half * (CH * 8) + ((jt + 1) * 32 + l31) * 8];
            // row-set A (rows wid*64 .. +31): 2 col-tiles -> min3 merge
            {
                const f32x16 d0 = __builtin_amdgcn_mfma_f32_32x32x16_f16(af0, bf0, zc, 0, 0, 0);
                const f32x16 d1 = __builtin_amdgcn_mfma_f32_32x32x16_f16(af0, bf1, zc, 0, 0, 0);
#pragma unroll
                for (int r = 0; r < 16; ++r)
                    rminA[r] = fminf(fminf(rminA[r], d0[r]), d1[r]);
            }
            // row-set B (rows wid*64+32 .. +63)
            {
                const f32x16 d0 = __builtin_amdgcn_mfma_f32_32x32x16_f16(af1, bf0, zc, 0, 0, 0);
                const f32x16 d1 = __builtin_amdgcn_mfma_f32_32x32x16_f16(af1, bf1, zc, 0, 0, 0);
#pragma unroll
                for (int r = 0; r < 16; ++r)
                    rminB[r] = fminf(fminf(rminB[r], d0[r]), d1[r]);
            }
        }
    }

    // min over the 32 col-residues (lane bits 0..4; bit 5 = k-half -> rows)
#pragma unroll
    for (int m = 1; m <= 16; m <<= 1) {
#pragma unroll
        for (int r = 0; r < 16; ++r) {
            rminA[r] = fminf(rminA[r], __shfl_xor(rminA[r], m, 64));
            rminB[r] = fminf(rminB[r], __shfl_xor(rminB[r], m, 64));
        }
    }

    // C layout (round-3-verified): col = lane&31, row = (r&3)+8*(r>>2)+4*half
    if (l31 == 0) {
#pragma unroll
        for (int r = 0; r < 16; ++r) {
            const int rl0 = wid * 64 + (r & 3) + 8 * (r >> 2) + 4 * half;
            const float v0 = fmaxf(rminA[r] + Aq[rl0], 0.0f);
            atomicMin(&dm[ibase + rl0], __float_as_uint(v0));
            const int rl1 = rl0 + 32;
            const float v1 = fmaxf(rminB[r] + Aq[rl1], 0.0f);
            atomicMin(&dm[ibase + rl1], __float_as_uint(v1));
        }
    }
}

// Sum dmin over all 2*65536 queries; out += blockSum / 65536.
__global__ __launch_bounds__(256) void chamfer_reduce_kernel(
    const unsigned int* __restrict__ dmin, float* __restrict__ out)
{
    const int i = blockIdx.x * 256 + threadIdx.x;
    float v = __uint_as_float(dmin[i]);
#pragma unroll
    for (int off = 32; off > 0; off >>= 1)
        v += __shfl_down(v, off, 64);
    __shared__ float ws2[4];
    const int lane = threadIdx.x & 63;
    const int wid  = threadIdx.x >> 6;
    if (lane == 0) ws2[wid] = v;
    __syncthreads();
    if (threadIdx.x == 0)
        atomicAdd(out, (ws2[0] + ws2[1] + ws2[2] + ws2[3]) * (1.0f / (float)NPTS));
}

// ============================================================================
extern "C" void kernel_launch(void* const* d_in, const int* in_sizes, int n_in,
                              void* d_out, int out_size, void* d_ws, size_t ws_size,
                              hipStream_t stream)
{
    const float* A = (const float*)d_in[0];   // pc0 (65536,3) f32
    const float* B = (const float*)d_in[1];   // pc1 (65536,3) f32
    float* out = (float*)d_out;               // scalar f32
    unsigned int* dmin = (unsigned int*)d_ws; // 512 KB, proven sufficient r2/r3

    hipMemsetAsync(dmin, 0x7F, 2 * NPTS * sizeof(unsigned int), stream);
    hipMemsetAsync(out, 0, sizeof(float), stream);

    chamfer_mfma_kernel<<<2 * NIBLK * NJSP, 512, 0, stream>>>(A, B, dmin);
    chamfer_reduce_kernel<<<(2 * NPTS) / 256, 256, 0, stream>>>(dmin, out);
}